// Round 5
// baseline (318.666 us; speedup 1.0000x reference)
//
#include <hip/hip_runtime.h>
#include <stdint.h>

#define SD 128
#define SH 128
#define SW 128
#define BATCH 2
#define CCH 64
#define KV 27
#define NCELL (BATCH * SD * SH * SW)  // 4,194,304
#define CHUNK 4096
#define NCHUNK (NCELL / CHUNK)        // 1024

typedef __attribute__((ext_vector_type(4))) float f32x4;
typedef __attribute__((ext_vector_type(8))) short s16x8;

__device__ __forceinline__ unsigned short f2bf_rne(float f) {
    union { float f; unsigned int u; } v; v.f = f;
    unsigned int u = v.u;
    return (unsigned short)((u + 0x7FFFu + ((u >> 16) & 1u)) >> 16);
}

__device__ __forceinline__ s16x8 pack_bf8(float4 a, float4 b) {
    s16x8 o;
    o[0] = (short)f2bf_rne(a.x); o[1] = (short)f2bf_rne(a.y);
    o[2] = (short)f2bf_rne(a.z); o[3] = (short)f2bf_rne(a.w);
    o[4] = (short)f2bf_rne(b.x); o[5] = (short)f2bf_rne(b.y);
    o[6] = (short)f2bf_rne(b.z); o[7] = (short)f2bf_rne(b.w);
    return o;
}

// ---------- common prep ----------

// W [27][64][64] f32 -> bf16, B-fragment layout: elem ((k*8 + ci/8)*64 + co)*8 + ci%8
__global__ void k_wprep(const float* __restrict__ W, unsigned short* __restrict__ Wt) {
    int idx = blockIdx.x * blockDim.x + threadIdx.x;
    if (idx >= KV * CCH * CCH) return;
    int k = idx / (CCH * CCH);
    int rem = idx - k * CCH * CCH;
    int ci = rem >> 6, co = rem & 63;
    int d = ((k * 8 + (ci >> 3)) * 64 + co) * 8 + (ci & 7);
    Wt[d] = f2bf_rne(W[idx]);
}

// scatter voxel index; atomicMax == last-index-wins (matches CPU sequential scatter; r4-validated)
__global__ void k_scatter(const int4* __restrict__ coors, int* __restrict__ grid, int n) {
    int i = blockIdx.x * blockDim.x + threadIdx.x;
    if (i >= n) return;
    int4 c = coors[i];  // (b, z, y, x)
    int flat = ((c.x * SD + c.y) * SH + c.z) * SW + c.w;
    atomicMax(&grid[flat], i);
}

// ---------- sorted-order machinery ----------

__global__ void k_count(const int4* __restrict__ grid4, int* __restrict__ counts) {
    int t = threadIdx.x;
    size_t base = (size_t)blockIdx.x * (CHUNK / 4) + t * 4;  // int4 units
    int cnt = 0;
#pragma unroll
    for (int i = 0; i < 4; ++i) {
        int4 v = grid4[base + i];
        cnt += (v.x >= 0) + (v.y >= 0) + (v.z >= 0) + (v.w >= 0);
    }
    __shared__ int s[256];
    s[t] = cnt; __syncthreads();
    for (int d = 128; d > 0; d >>= 1) {
        if (t < d) s[t] += s[t + d];
        __syncthreads();
    }
    if (t == 0) counts[blockIdx.x] = s[0];
}

// single block, 1024 threads: exclusive prefix of chunk counts; ctr[0] = total occupied U
__global__ void k_scan(const int* __restrict__ counts, int* __restrict__ excl, int* __restrict__ ctr) {
    __shared__ int s[NCHUNK];
    int t = threadIdx.x;
    int v = counts[t];
    s[t] = v; __syncthreads();
    for (int d = 1; d < NCHUNK; d <<= 1) {
        int a = (t >= d) ? s[t - d] : 0;
        __syncthreads();
        s[t] += a;
        __syncthreads();
    }
    excl[t] = s[t] - v;
    if (t == NCHUNK - 1) ctr[0] = s[t];
}

// compact occupied cells in flat order: perm[i] = orig idx; grid[cell] := sorted idx
__global__ void k_compact(int* __restrict__ grid, const int* __restrict__ excl,
                          int* __restrict__ perm) {
    int t = threadIdx.x;
    size_t cellbase = (size_t)blockIdx.x * CHUNK + t * 16;
    int v[16];
    const int4* g4 = (const int4*)(grid + cellbase);
#pragma unroll
    for (int i = 0; i < 4; ++i) {
        int4 a = g4[i];
        v[i * 4 + 0] = a.x; v[i * 4 + 1] = a.y; v[i * 4 + 2] = a.z; v[i * 4 + 3] = a.w;
    }
    int cnt = 0;
#pragma unroll
    for (int i = 0; i < 16; ++i) cnt += (v[i] >= 0);
    __shared__ int s[256];
    s[t] = cnt; __syncthreads();
    for (int d = 1; d < 256; d <<= 1) {
        int a = (t >= d) ? s[t - d] : 0;
        __syncthreads();
        s[t] += a;
        __syncthreads();
    }
    int idx = excl[blockIdx.x] + s[t] - cnt;
#pragma unroll
    for (int i = 0; i < 16; ++i) {
        if (v[i] >= 0) {
            perm[idx] = v[i];
            grid[cellbase + i] = idx;
            idx++;
        }
    }
}

// rows whose cell was claimed by a later duplicate get appended slots U..N-1
__global__ void k_losers(const int4* __restrict__ coors, const int* __restrict__ grid,
                         int* __restrict__ perm, int* __restrict__ ctr, int n) {
    int j = blockIdx.x * blockDim.x + threadIdx.x;
    if (j >= n) return;
    int4 c = coors[j];
    int flat = ((c.x * SD + c.y) * SH + c.z) * SW + c.w;
    int si = grid[flat];           // winner's sorted slot (always < U)
    if (perm[si] != j) {
        int s = atomicAdd(ctr, 1);
        perm[s] = j;
    }
}

// fs[i] = bf16(features[perm[i]]) (sorted order); fb[i] = flat coord of perm[i]
__global__ void k_permfeat(const float4* __restrict__ feats4, const int4* __restrict__ coors,
                           const int* __restrict__ perm, s16x8* __restrict__ fs,
                           int* __restrict__ fb, int n) {
    int tid = blockIdx.x * blockDim.x + threadIdx.x;
    int i = tid >> 3, j = tid & 7;
    if (i >= n) return;
    int src = perm[i];
    float4 p0 = feats4[(size_t)src * 16 + j * 2];
    float4 p1 = feats4[(size_t)src * 16 + j * 2 + 1];
    fs[(size_t)i * 8 + j] = pack_bf8(p0, p1);
    if (j == 0) {
        int4 c = coors[src];
        fb[i] = ((c.x * SD + c.y) * SH + c.z) * SW + c.w;
    }
}

// ---------- sorted conv: one wave = 32 consecutive sorted voxels x 64 cout ----------
// A-frag (16x16x32): lane holds row lane&15, k=(lane>>4)*8+j -> one 16B load.
// C/D: col=lane&15, row=(lane>>4)*4+reg (m89-verified, r4-validated).
template <int OUT_PERM>
__global__ __launch_bounds__(256) void k_conv_s(const s16x8* __restrict__ fin,  // sorted bf16 [n][8]
                                                const s16x8* __restrict__ wt,
                                                const int* __restrict__ fb,
                                                const int* __restrict__ grid,   // sorted ids
                                                const int* __restrict__ perm,
                                                void* __restrict__ outp, int n) {
    // bijective XCD-chunked swizzle (m204): consecutive tiles -> same XCD L2
    int nwg = gridDim.x, orig = blockIdx.x;
    int q = nwg >> 3, rr = nwg & 7;
    int xcd = orig & 7, bidx = orig >> 3;
    int blk = (xcd < rr ? xcd * (q + 1) : rr * (q + 1) + (xcd - rr) * q) + bidx;

    int wid = blk * (blockDim.x >> 6) + (threadIdx.x >> 6);
    int lane = threadIdx.x & 63;
    int base = wid * 32;
    if (base >= n) return;
    int r = lane & 15;
    int g = lane >> 4;
    int li = lane & 31;
    int myrow = base + li;
    int rowok = (myrow < n) ? 1 : 0;
    int fbv = fb[rowok ? myrow : 0];
    int pl = 0;
    if (OUT_PERM) pl = rowok ? perm[myrow] : 0;
    int z = (fbv >> 14) & 127, y = (fbv >> 7) & 127, x = fbv & 127;

    f32x4 acc[2][4] = {};

    auto lookup = [&](int k) -> int {
        int dz = k / 9 - 1, dy = (k / 3) % 3 - 1, dx = k % 3 - 1;
        int zz = z + dz, yy = y + dy, xx = x + dx;
        int v = -1;
        if (rowok && (unsigned)zz < SD && (unsigned)yy < SH && (unsigned)xx < SW)
            v = grid[fbv + dz * (SH * SW) + dy * SW + dx];
        return v;
    };

    int nbr = lookup(0);
    for (int k = 0; k < KV; ++k) {
        int nbr_next = (k + 1 < KV) ? lookup(k + 1) : -1;  // prefetch next offset
        int nb0 = __shfl(nbr, r);
        int nb1 = __shfl(nbr, 16 + r);
        nbr = nbr_next;
        unsigned long long m0 = __ballot(nb0 >= 0);
        unsigned long long m1 = __ballot(nb1 >= 0);
        if ((m0 | m1) == 0ULL) continue;

        s16x8 bf[2][4];
#pragma unroll
        for (int s = 0; s < 2; ++s)
#pragma unroll
            for (int t = 0; t < 4; ++t)
                bf[s][t] = wt[(k * 8 + s * 4 + g) * 64 + t * 16 + r];

        int nbh[2] = {nb0, nb1};
        unsigned long long mm[2] = {m0, m1};
#pragma unroll
        for (int h = 0; h < 2; ++h) {
            if (!mm[h]) continue;
            int nbx = nbh[h];
            s16x8 a0 = {}, a1 = {};
            if (nbx >= 0) {
                a0 = fin[(size_t)nbx * 8 + g];
                a1 = fin[(size_t)nbx * 8 + 4 + g];
            }
#pragma unroll
            for (int t = 0; t < 4; ++t) {
                acc[h][t] = __builtin_amdgcn_mfma_f32_16x16x32_bf16(a0, bf[0][t], acc[h][t], 0, 0, 0);
                acc[h][t] = __builtin_amdgcn_mfma_f32_16x16x32_bf16(a1, bf[1][t], acc[h][t], 0, 0, 0);
            }
        }
    }

    if (OUT_PERM) {
        float* __restrict__ o = (float*)outp;  // scatter to original row order
#pragma unroll
        for (int h = 0; h < 2; ++h)
#pragma unroll
            for (int t = 0; t < 4; ++t)
#pragma unroll
                for (int j = 0; j < 4; ++j) {
                    int w = h * 16 + g * 4 + j;
                    if (base + w < n) {
                        int orow = __shfl(pl, w);
                        o[(size_t)orow * 64 + t * 16 + r] = acc[h][t][j];
                    }
                }
    } else {
        unsigned short* __restrict__ o = (unsigned short*)outp;  // sorted bf16 intermediate
#pragma unroll
        for (int h = 0; h < 2; ++h)
#pragma unroll
            for (int t = 0; t < 4; ++t)
#pragma unroll
                for (int j = 0; j < 4; ++j) {
                    int row = base + h * 16 + g * 4 + j;
                    if (row < n) o[(size_t)row * 64 + t * 16 + r] = f2bf_rne(acc[h][t][j]);
                }
    }
}

// ---------- legacy (round-4, unsorted) path: kept as ws-size fallback ----------

__global__ void k_f2bf(const float4* __restrict__ in, ushort4* __restrict__ out, int n4) {
    int i = blockIdx.x * blockDim.x + threadIdx.x;
    if (i >= n4) return;
    float4 a = in[i];
    ushort4 o;
    o.x = f2bf_rne(a.x); o.y = f2bf_rne(a.y);
    o.z = f2bf_rne(a.z); o.w = f2bf_rne(a.w);
    out[i] = o;
}

template <int IN_F32, int OUT_BF16>
__global__ __launch_bounds__(256) void k_conv_legacy(const void* __restrict__ finv,
                                                     const s16x8* __restrict__ wt,
                                                     const int4* __restrict__ coors,
                                                     const int* __restrict__ grid,
                                                     void* __restrict__ outp, int n) {
    int wid = blockIdx.x * (blockDim.x >> 6) + (threadIdx.x >> 6);
    int lane = threadIdx.x & 63;
    int base = wid * 32;
    if (base >= n) return;
    int r = lane & 15;
    int g = lane >> 4;
    int li = lane & 31;
    int myrow = base + li;
    int rowok = (myrow < n) ? 1 : 0;
    int4 c = coors[rowok ? myrow : 0];
    int z = c.y, y = c.z, x = c.w;
    int flatbase = ((c.x * SD + z) * SH + y) * SW + x;

    f32x4 acc[2][4] = {};

    auto lookup = [&](int k) -> int {
        int dz = k / 9 - 1, dy = (k / 3) % 3 - 1, dx = k % 3 - 1;
        int zz = z + dz, yy = y + dy, xx = x + dx;
        int v = -1;
        if (rowok && (unsigned)zz < SD && (unsigned)yy < SH && (unsigned)xx < SW)
            v = grid[flatbase + dz * (SH * SW) + dy * SW + dx];
        return v;
    };

    int nbr = lookup(0);
    for (int k = 0; k < KV; ++k) {
        int nbr_next = (k + 1 < KV) ? lookup(k + 1) : -1;
        int nb0 = __shfl(nbr, r);
        int nb1 = __shfl(nbr, 16 + r);
        nbr = nbr_next;
        unsigned long long m0 = __ballot(nb0 >= 0);
        unsigned long long m1 = __ballot(nb1 >= 0);
        if ((m0 | m1) == 0ULL) continue;

        s16x8 bf[2][4];
#pragma unroll
        for (int s = 0; s < 2; ++s)
#pragma unroll
            for (int t = 0; t < 4; ++t)
                bf[s][t] = wt[(k * 8 + s * 4 + g) * 64 + t * 16 + r];

        int nbh[2] = {nb0, nb1};
        unsigned long long mm[2] = {m0, m1};
#pragma unroll
        for (int h = 0; h < 2; ++h) {
            if (!mm[h]) continue;
            int nbx = nbh[h];
            s16x8 a0 = {}, a1 = {};
            if (nbx >= 0) {
                if (IN_F32) {
                    const float4* ff = (const float4*)finv;
                    size_t rb = (size_t)nbx * 16 + g * 2;
                    float4 p0 = ff[rb], p1 = ff[rb + 1];
                    float4 p2 = ff[rb + 8], p3 = ff[rb + 9];
                    a0 = pack_bf8(p0, p1);
                    a1 = pack_bf8(p2, p3);
                } else {
                    const s16x8* fbp = (const s16x8*)finv;
                    a0 = fbp[(size_t)nbx * 8 + g];
                    a1 = fbp[(size_t)nbx * 8 + 4 + g];
                }
            }
#pragma unroll
            for (int t = 0; t < 4; ++t) {
                acc[h][t] = __builtin_amdgcn_mfma_f32_16x16x32_bf16(a0, bf[0][t], acc[h][t], 0, 0, 0);
                acc[h][t] = __builtin_amdgcn_mfma_f32_16x16x32_bf16(a1, bf[1][t], acc[h][t], 0, 0, 0);
            }
        }
    }

    if (OUT_BF16) {
        unsigned short* __restrict__ o = (unsigned short*)outp;
#pragma unroll
        for (int h = 0; h < 2; ++h)
#pragma unroll
            for (int t = 0; t < 4; ++t)
#pragma unroll
                for (int j = 0; j < 4; ++j) {
                    int row = base + h * 16 + g * 4 + j;
                    if (row < n) o[(size_t)row * 64 + t * 16 + r] = f2bf_rne(acc[h][t][j]);
                }
    } else {
        float* __restrict__ o = (float*)outp;
#pragma unroll
        for (int h = 0; h < 2; ++h)
#pragma unroll
            for (int t = 0; t < 4; ++t)
#pragma unroll
                for (int j = 0; j < 4; ++j) {
                    int row = base + h * 16 + g * 4 + j;
                    if (row < n) o[(size_t)row * 64 + t * 16 + r] = acc[h][t][j];
                }
    }
}

extern "C" void kernel_launch(void* const* d_in, const int* in_sizes, int n_in,
                              void* d_out, int out_size, void* d_ws, size_t ws_size,
                              hipStream_t stream) {
    const float* feats = (const float*)d_in[0];
    const int4* coors = (const int4*)d_in[1];
    const float* W0 = (const float*)d_in[2];
    const float* W1 = (const float*)d_in[3];
    int N = in_sizes[0] / CCH;

    char* p0 = (char*)d_ws;
    char* p = p0;
    auto carve = [&](size_t bytes) -> char* {
        char* q = p;
        p += (bytes + 255) & ~(size_t)255;
        return q;
    };

    size_t grid_bytes = (size_t)NCELL * 4;                              // 16.78 MB
    int* grid = (int*)carve(grid_bytes);
    unsigned short* wt0 = (unsigned short*)carve((size_t)KV * CCH * CCH * 2);
    unsigned short* wt1 = (unsigned short*)carve((size_t)KV * CCH * CCH * 2);

    char* psave = p;
    int* counts = (int*)carve(NCHUNK * 4);
    int* excl = (int*)carve(NCHUNK * 4);
    int* ctr = (int*)carve(256);
    int* perm = (int*)carve((size_t)N * 4);
    int* fb = (int*)carve((size_t)N * 4);
    s16x8* fs = (s16x8*)carve((size_t)N * CCH * 2);
    s16x8* ibf_s = (s16x8*)carve((size_t)N * CCH * 2);
    bool sorted_ok = (size_t)(p - p0) <= ws_size;

    int nw = KV * CCH * CCH;
    int tiles = (N + 31) / 32;
    int blocks = (tiles + 3) / 4;

    hipMemsetAsync(grid, 0xFF, grid_bytes, stream);
    k_wprep<<<(nw + 255) / 256, 256, 0, stream>>>(W0, wt0);
    k_wprep<<<(nw + 255) / 256, 256, 0, stream>>>(W1, wt1);
    k_scatter<<<(N + 255) / 256, 256, 0, stream>>>(coors, grid, N);

    if (sorted_ok) {
        k_count<<<NCHUNK, 256, 0, stream>>>((const int4*)grid, counts);
        k_scan<<<1, NCHUNK, 0, stream>>>(counts, excl, ctr);
        k_compact<<<NCHUNK, 256, 0, stream>>>(grid, excl, perm);
        k_losers<<<(N + 255) / 256, 256, 0, stream>>>(coors, grid, perm, ctr, N);
        k_permfeat<<<((N * 8) + 255) / 256, 256, 0, stream>>>((const float4*)feats, coors, perm, fs, fb, N);
        k_conv_s<0><<<blocks, 256, 0, stream>>>(fs, (const s16x8*)wt0, fb, grid, perm, ibf_s, N);
        k_conv_s<1><<<blocks, 256, 0, stream>>>(ibf_s, (const s16x8*)wt1, fb, grid, perm, d_out, N);
    } else {
        p = psave;
        s16x8* ibf = (s16x8*)carve((size_t)N * CCH * 2);
        size_t base_need = (size_t)(p - p0);
        s16x8* fbf = nullptr;
        if (ws_size >= base_need + (size_t)N * CCH * 2 + 256)
            fbf = (s16x8*)carve((size_t)N * CCH * 2);
        if (fbf) {
            int n4 = N * CCH / 4;
            k_f2bf<<<(n4 + 255) / 256, 256, 0, stream>>>((const float4*)feats, (ushort4*)fbf, n4);
            k_conv_legacy<0, 1><<<blocks, 256, 0, stream>>>(fbf, (const s16x8*)wt0, coors, grid, ibf, N);
        } else {
            k_conv_legacy<1, 1><<<blocks, 256, 0, stream>>>(feats, (const s16x8*)wt0, coors, grid, ibf, N);
        }
        k_conv_legacy<0, 0><<<blocks, 256, 0, stream>>>(ibf, (const s16x8*)wt1, coors, grid, d_out, N);
    }
}

// Round 9
// 298.772 us; speedup vs baseline: 1.0666x; 1.0666x over previous
//
#include <hip/hip_runtime.h>
#include <stdint.h>

#define SD 128
#define SH 128
#define SW 128
#define BATCH 2
#define CCH 64
#define KV 27
#define NCELL (BATCH * SD * SH * SW)  // 4,194,304
#define CHUNK 4096
#define NCHUNK (NCELL / CHUNK)        // 1024

typedef __attribute__((ext_vector_type(4))) float f32x4;
typedef __attribute__((ext_vector_type(8))) short s16x8;

__device__ __forceinline__ unsigned short f2bf_rne(float f) {
    union { float f; unsigned int u; } v; v.f = f;
    unsigned int u = v.u;
    return (unsigned short)((u + 0x7FFFu + ((u >> 16) & 1u)) >> 16);
}

__device__ __forceinline__ s16x8 pack_bf8(float4 a, float4 b) {
    s16x8 o;
    o[0] = (short)f2bf_rne(a.x); o[1] = (short)f2bf_rne(a.y);
    o[2] = (short)f2bf_rne(a.z); o[3] = (short)f2bf_rne(a.w);
    o[4] = (short)f2bf_rne(b.x); o[5] = (short)f2bf_rne(b.y);
    o[6] = (short)f2bf_rne(b.z); o[7] = (short)f2bf_rne(b.w);
    return o;
}

// ---------- prep ----------

// W [27][64][64] f32 -> bf16, B-fragment layout:
// slice k is 512 s16x8; frag (s,g,t,r) at (s*4+g)*64 + t*16 + r, vector = 8 contiguous ci
__global__ void k_wprep(const float* __restrict__ W, unsigned short* __restrict__ Wt) {
    int idx = blockIdx.x * blockDim.x + threadIdx.x;
    if (idx >= KV * CCH * CCH) return;
    int k = idx / (CCH * CCH);
    int rem = idx - k * CCH * CCH;
    int ci = rem >> 6, co = rem & 63;
    int d = ((k * 8 + (ci >> 3)) * 64 + co) * 8 + (ci & 7);
    Wt[d] = f2bf_rne(W[idx]);
}

// scatter voxel index; atomicMax == last-index-wins (r4/r5-validated)
__global__ void k_scatter(const int4* __restrict__ coors, int* __restrict__ grid, int n) {
    int i = blockIdx.x * blockDim.x + threadIdx.x;
    if (i >= n) return;
    int4 c = coors[i];  // (b, z, y, x)
    int flat = ((c.x * SD + c.y) * SH + c.z) * SW + c.w;
    atomicMax(&grid[flat], i);
}

// ---------- sorted-order machinery (r5-validated) ----------

__global__ void k_count(const int4* __restrict__ grid4, int* __restrict__ counts) {
    int t = threadIdx.x;
    size_t base = (size_t)blockIdx.x * (CHUNK / 4) + t * 4;
    int cnt = 0;
#pragma unroll
    for (int i = 0; i < 4; ++i) {
        int4 v = grid4[base + i];
        cnt += (v.x >= 0) + (v.y >= 0) + (v.z >= 0) + (v.w >= 0);
    }
    __shared__ int s[256];
    s[t] = cnt; __syncthreads();
    for (int d = 128; d > 0; d >>= 1) {
        if (t < d) s[t] += s[t + d];
        __syncthreads();
    }
    if (t == 0) counts[blockIdx.x] = s[0];
}

// 1024 threads: shfl-based exclusive scan of chunk counts; ctr[0] = total occupied
__global__ void k_scan(const int* __restrict__ counts, int* __restrict__ excl, int* __restrict__ ctr) {
    int t = threadIdx.x, lane = t & 63, w = t >> 6;
    int v = counts[t];
    int s = v;
#pragma unroll
    for (int d = 1; d < 64; d <<= 1) {
        int u = __shfl_up(s, d);
        if (lane >= d) s += u;
    }
    __shared__ int wsum[16];
    if (lane == 63) wsum[w] = s;
    __syncthreads();
    if (w == 0 && lane < 16) {
        int x = wsum[lane];
#pragma unroll
        for (int d = 1; d < 16; d <<= 1) {
            int u = __shfl_up(x, d);
            if (lane >= d) x += u;
        }
        wsum[lane] = x;
    }
    __syncthreads();
    int add = (w > 0) ? wsum[w - 1] : 0;
    excl[t] = add + s - v;
    if (t == 1023) ctr[0] = add + s;
}

// compact occupied cells in flat order: perm[i] = orig idx; grid[cell] := sorted idx
__global__ void k_compact(int* __restrict__ grid, const int* __restrict__ excl,
                          int* __restrict__ perm) {
    int t = threadIdx.x;
    size_t cellbase = (size_t)blockIdx.x * CHUNK + t * 16;
    int v[16];
    const int4* g4 = (const int4*)(grid + cellbase);
#pragma unroll
    for (int i = 0; i < 4; ++i) {
        int4 a = g4[i];
        v[i * 4 + 0] = a.x; v[i * 4 + 1] = a.y; v[i * 4 + 2] = a.z; v[i * 4 + 3] = a.w;
    }
    int cnt = 0;
#pragma unroll
    for (int i = 0; i < 16; ++i) cnt += (v[i] >= 0);
    __shared__ int s[256];
    s[t] = cnt; __syncthreads();
    for (int d = 1; d < 256; d <<= 1) {
        int a = (t >= d) ? s[t - d] : 0;
        __syncthreads();
        s[t] += a;
        __syncthreads();
    }
    int idx = excl[blockIdx.x] + s[t] - cnt;
#pragma unroll
    for (int i = 0; i < 16; ++i) {
        if (v[i] >= 0) {
            perm[idx] = v[i];
            grid[cellbase + i] = idx;
            idx++;
        }
    }
}

// duplicate-coordinate losers get appended slots U..N-1
__global__ void k_losers(const int4* __restrict__ coors, const int* __restrict__ grid,
                         int* __restrict__ perm, int* __restrict__ ctr, int n) {
    int j = blockIdx.x * blockDim.x + threadIdx.x;
    if (j >= n) return;
    int4 c = coors[j];
    int flat = ((c.x * SD + c.y) * SH + c.z) * SW + c.w;
    int si = grid[flat];
    if (perm[si] != j) {
        int s = atomicAdd(ctr, 1);
        perm[s] = j;
    }
}

// fs[i] = bf16(features[perm[i]]); fb[i] = flat coord of perm[i]
__global__ void k_permfeat(const float4* __restrict__ feats4, const int4* __restrict__ coors,
                           const int* __restrict__ perm, s16x8* __restrict__ fs,
                           int* __restrict__ fb, int n) {
    int tid = blockIdx.x * blockDim.x + threadIdx.x;
    int i = tid >> 3, j = tid & 7;
    if (i >= n) return;
    int src = perm[i];
    float4 p0 = feats4[(size_t)src * 16 + j * 2];
    float4 p1 = feats4[(size_t)src * 16 + j * 2 + 1];
    fs[(size_t)i * 8 + j] = pack_bf8(p0, p1);
    if (j == 0) {
        int4 c = coors[src];
        fb[i] = ((c.x * SD + c.y) * SH + c.z) * SW + c.w;
    }
}

// ---------- sorted conv v2: LDS-staged weights, lockstep k ----------
// One wave = 32 sorted voxels x 64 cout; block = 4 waves sharing the weight stage.
// A-frag (16x16x32): lane holds row lane&15, k=(lane>>4)*8+j -> one 16B load.
// C/D: col=lane&15, row=(lane>>4)*4+reg (m89-verified, r4/r5-validated).
template <int OUT_PERM>
__global__ __launch_bounds__(256) void k_conv_s(const s16x8* __restrict__ fin,
                                                const s16x8* __restrict__ wt,
                                                const int* __restrict__ fb,
                                                const int* __restrict__ grid,
                                                const int* __restrict__ perm,
                                                void* __restrict__ outp, int n) {
    __shared__ s16x8 wbuf[2][512];  // 2 x 8 KB double-buffered weight slice

    // bijective XCD-chunked swizzle (m204)
    int nwg = gridDim.x, orig = blockIdx.x;
    int q = nwg >> 3, rr = nwg & 7;
    int xcd = orig & 7, bidx = orig >> 3;
    int blk = (xcd < rr ? xcd * (q + 1) : rr * (q + 1) + (xcd - rr) * q) + bidx;

    int tid = threadIdx.x;
    int w = tid >> 6, lane = tid & 63;
    int wid = blk * 4 + w;
    int base = wid * 32;                 // may be >= n for tail waves: no early return (barriers)
    int r = lane & 15;
    int g = lane >> 4;
    int li = lane & 31;
    int myrow = base + li;
    int rowok = (myrow < n) ? 1 : 0;
    int fbv = fb[rowok ? myrow : 0];
    int pl = 0;
    if (OUT_PERM) pl = rowok ? perm[myrow] : 0;
    int z = (fbv >> 14) & 127, y = (fbv >> 7) & 127, x = fbv & 127;

    f32x4 acc[2][4] = {};

    auto lookup = [&](int k) -> int {
        int dz = k / 9 - 1, dy = (k / 3) % 3 - 1, dx = k % 3 - 1;
        int zz = z + dz, yy = y + dy, xx = x + dx;
        int v = -1;
        if (rowok && (unsigned)zz < SD && (unsigned)yy < SH && (unsigned)xx < SW)
            v = grid[fbv + dz * (SH * SW) + dy * SW + dx];
        return v;
    };

    // prologue: stage slice 0
    {
        s16x8 s0 = wt[tid];
        s16x8 s1 = wt[256 + tid];
        wbuf[0][tid] = s0;
        wbuf[0][256 + tid] = s1;
    }
    __syncthreads();

    int nbr = lookup(0);
    for (int k = 0; k < KV; ++k) {
        // issue next-slice weight loads early (latency hides under compute)
        int kn = (k + 1 < KV) ? k + 1 : KV - 1;
        s16x8 st0 = wt[(size_t)kn * 512 + tid];
        s16x8 st1 = wt[(size_t)kn * 512 + 256 + tid];

        int nbr_next = (k + 1 < KV) ? lookup(k + 1) : -1;
        int nb0 = __shfl(nbr, r);
        int nb1 = __shfl(nbr, 16 + r);
        nbr = nbr_next;
        unsigned long long m0 = __ballot(nb0 >= 0);
        unsigned long long m1 = __ballot(nb1 >= 0);

        if (m0 | m1) {
            const s16x8* wb = &wbuf[k & 1][0];
            s16x8 bf[2][4];
#pragma unroll
            for (int s = 0; s < 2; ++s)
#pragma unroll
                for (int t = 0; t < 4; ++t)
                    bf[s][t] = wb[(s * 4 + g) * 64 + t * 16 + r];

            int nbh[2] = {nb0, nb1};
            unsigned long long mm[2] = {m0, m1};
#pragma unroll
            for (int h = 0; h < 2; ++h) {
                if (!mm[h]) continue;
                int nbx = nbh[h];
                s16x8 a0 = {}, a1 = {};
                if (nbx >= 0) {
                    a0 = fin[(size_t)nbx * 8 + g];
                    a1 = fin[(size_t)nbx * 8 + 4 + g];
                }
#pragma unroll
                for (int t = 0; t < 4; ++t) {
                    acc[h][t] = __builtin_amdgcn_mfma_f32_16x16x32_bf16(a0, bf[0][t], acc[h][t], 0, 0, 0);
                    acc[h][t] = __builtin_amdgcn_mfma_f32_16x16x32_bf16(a1, bf[1][t], acc[h][t], 0, 0, 0);
                }
            }
        }

        // write next slice into the other buffer (no one reads it this iter)
        wbuf[(k + 1) & 1][tid] = st0;
        wbuf[(k + 1) & 1][256 + tid] = st1;
        __syncthreads();
    }

    if (OUT_PERM) {
        float* __restrict__ o = (float*)outp;  // scatter back to original row order
#pragma unroll
        for (int h = 0; h < 2; ++h)
#pragma unroll
            for (int t = 0; t < 4; ++t)
#pragma unroll
                for (int j = 0; j < 4; ++j) {
                    int ww = h * 16 + g * 4 + j;
                    if (base + ww < n) {
                        int orow = __shfl(pl, ww);
                        o[(size_t)orow * 64 + t * 16 + r] = acc[h][t][j];
                    }
                }
    } else {
        unsigned short* __restrict__ o = (unsigned short*)outp;  // sorted bf16 intermediate
#pragma unroll
        for (int h = 0; h < 2; ++h)
#pragma unroll
            for (int t = 0; t < 4; ++t)
#pragma unroll
                for (int j = 0; j < 4; ++j) {
                    int row = base + h * 16 + g * 4 + j;
                    if (row < n) o[(size_t)row * 64 + t * 16 + r] = f2bf_rne(acc[h][t][j]);
                }
    }
}

extern "C" void kernel_launch(void* const* d_in, const int* in_sizes, int n_in,
                              void* d_out, int out_size, void* d_ws, size_t ws_size,
                              hipStream_t stream) {
    const float* feats = (const float*)d_in[0];
    const int4* coors = (const int4*)d_in[1];
    const float* W0 = (const float*)d_in[2];
    const float* W1 = (const float*)d_in[3];
    int N = in_sizes[0] / CCH;

    char* p = (char*)d_ws;
    auto carve = [&](size_t bytes) -> char* {
        char* q = p;
        p += (bytes + 255) & ~(size_t)255;
        return q;
    };

    size_t grid_bytes = (size_t)NCELL * 4;
    int* grid = (int*)carve(grid_bytes);                                 // 16.78 MB
    unsigned short* wt0 = (unsigned short*)carve((size_t)KV * CCH * CCH * 2);
    unsigned short* wt1 = (unsigned short*)carve((size_t)KV * CCH * CCH * 2);
    int* counts = (int*)carve(NCHUNK * 4);
    int* excl = (int*)carve(NCHUNK * 4);
    int* ctr = (int*)carve(256);
    int* perm = (int*)carve((size_t)N * 4);
    int* fb = (int*)carve((size_t)N * 4);
    s16x8* fs = (s16x8*)carve((size_t)N * CCH * 2);                      // 25.6 MB
    s16x8* ibf_s = (s16x8*)carve((size_t)N * CCH * 2);                   // 25.6 MB (~70.3 MB total, fits: r5)

    int nw = KV * CCH * CCH;
    int tiles = (N + 31) / 32;
    int blocks = (tiles + 3) / 4;

    hipMemsetAsync(grid, 0xFF, grid_bytes, stream);
    k_wprep<<<(nw + 255) / 256, 256, 0, stream>>>(W0, wt0);
    k_wprep<<<(nw + 255) / 256, 256, 0, stream>>>(W1, wt1);
    k_scatter<<<(N + 255) / 256, 256, 0, stream>>>(coors, grid, N);
    k_count<<<NCHUNK, 256, 0, stream>>>((const int4*)grid, counts);
    k_scan<<<1, 1024, 0, stream>>>(counts, excl, ctr);
    k_compact<<<NCHUNK, 256, 0, stream>>>(grid, excl, perm);
    k_losers<<<(N + 255) / 256, 256, 0, stream>>>(coors, grid, perm, ctr, N);
    k_permfeat<<<((N * 8) + 255) / 256, 256, 0, stream>>>((const float4*)feats, coors, perm, fs, fb, N);
    k_conv_s<0><<<blocks, 256, 0, stream>>>(fs, (const s16x8*)wt0, fb, grid, perm, ibf_s, N);
    k_conv_s<1><<<blocks, 256, 0, stream>>>(ibf_s, (const s16x8*)wt1, fb, grid, perm, d_out, N);
}

// Round 11
// 296.388 us; speedup vs baseline: 1.0752x; 1.0080x over previous
//
#include <hip/hip_runtime.h>
#include <stdint.h>

#define SD 128
#define SH 128
#define SW 128
#define BATCH 2
#define CCH 64
#define KV 27
#define NCELL (BATCH * SD * SH * SW)  // 4,194,304
#define CHUNK 4096
#define NCHUNK (NCELL / CHUNK)        // 1024
#define NWELEM (KV * CCH * CCH)

typedef __attribute__((ext_vector_type(4))) float f32x4;
typedef __attribute__((ext_vector_type(8))) short s16x8;

__device__ __forceinline__ unsigned short f2bf_rne(float f) {
    union { float f; unsigned int u; } v; v.f = f;
    unsigned int u = v.u;
    return (unsigned short)((u + 0x7FFFu + ((u >> 16) & 1u)) >> 16);
}

__device__ __forceinline__ s16x8 pack_bf8(float4 a, float4 b) {
    s16x8 o;
    o[0] = (short)f2bf_rne(a.x); o[1] = (short)f2bf_rne(a.y);
    o[2] = (short)f2bf_rne(a.z); o[3] = (short)f2bf_rne(a.w);
    o[4] = (short)f2bf_rne(b.x); o[5] = (short)f2bf_rne(b.y);
    o[6] = (short)f2bf_rne(b.z); o[7] = (short)f2bf_rne(b.w);
    return o;
}

// ---------- prep ----------

// Both W0,W1 f32 -> bf16 B-fragment layout in one launch:
// slice k is 512 s16x8; frag (s,g,t,r) at (s*4+g)*64 + t*16 + r, vector = 8 contiguous ci
__global__ void k_wprep2(const float* __restrict__ W0, const float* __restrict__ W1,
                         unsigned short* __restrict__ Wt0, unsigned short* __restrict__ Wt1) {
    int idx = blockIdx.x * blockDim.x + threadIdx.x;
    if (idx >= 2 * NWELEM) return;
    int which = idx >= NWELEM;
    int id = idx - which * NWELEM;
    const float* W = which ? W1 : W0;
    unsigned short* Wt = which ? Wt1 : Wt0;
    int k = id / (CCH * CCH);
    int rem = id - k * CCH * CCH;
    int ci = rem >> 6, co = rem & 63;
    int d = ((k * 8 + (ci >> 3)) * 64 + co) * 8 + (ci & 7);
    Wt[d] = f2bf_rne(W[id]);
}

// scatter voxel index; atomicMax == last-index-wins (r4/r5/r9-validated)
__global__ void k_scatter(const int4* __restrict__ coors, int* __restrict__ grid, int n) {
    int i = blockIdx.x * blockDim.x + threadIdx.x;
    if (i >= n) return;
    int4 c = coors[i];  // (b, z, y, x)
    int flat = ((c.x * SD + c.y) * SH + c.z) * SW + c.w;
    atomicMax(&grid[flat], i);
}

// ---------- sorted-order machinery ----------

__global__ void k_count(const int4* __restrict__ grid4, int* __restrict__ counts) {
    int t = threadIdx.x;
    size_t base = (size_t)blockIdx.x * (CHUNK / 4) + t * 4;
    int cnt = 0;
#pragma unroll
    for (int i = 0; i < 4; ++i) {
        int4 v = grid4[base + i];
        cnt += (v.x >= 0) + (v.y >= 0) + (v.z >= 0) + (v.w >= 0);
    }
    __shared__ int s[256];
    s[t] = cnt; __syncthreads();
    for (int d = 128; d > 0; d >>= 1) {
        if (t < d) s[t] += s[t + d];
        __syncthreads();
    }
    if (t == 0) counts[blockIdx.x] = s[0];
}

// compact occupied cells in flat order; self-computed prefix (replaces k_scan):
// perm[i] = orig idx; grid[cell] := sorted idx; last block writes ctr[0] = U
__global__ void k_compact(int* __restrict__ grid, const int* __restrict__ counts,
                          int* __restrict__ perm, int* __restrict__ ctr) {
    int t = threadIdx.x, b = blockIdx.x;
    __shared__ int s[256];
    // prefix over previous chunks (<= 4KB of L2-hot counts)
    int part = 0;
    for (int j = t; j < b; j += 256) part += counts[j];
    s[t] = part; __syncthreads();
    for (int d = 128; d > 0; d >>= 1) {
        if (t < d) s[t] += s[t + d];
        __syncthreads();
    }
    int exclv = s[0];
    __syncthreads();

    size_t cellbase = (size_t)b * CHUNK + t * 16;
    int v[16];
    const int4* g4 = (const int4*)(grid + cellbase);
#pragma unroll
    for (int i = 0; i < 4; ++i) {
        int4 a = g4[i];
        v[i * 4 + 0] = a.x; v[i * 4 + 1] = a.y; v[i * 4 + 2] = a.z; v[i * 4 + 3] = a.w;
    }
    int cnt = 0;
#pragma unroll
    for (int i = 0; i < 16; ++i) cnt += (v[i] >= 0);
    s[t] = cnt; __syncthreads();
    for (int d = 1; d < 256; d <<= 1) {
        int a = (t >= d) ? s[t - d] : 0;
        __syncthreads();
        s[t] += a;
        __syncthreads();
    }
    int idx = exclv + s[t] - cnt;
#pragma unroll
    for (int i = 0; i < 16; ++i) {
        if (v[i] >= 0) {
            perm[idx] = v[i];
            grid[cellbase + i] = idx;
            idx++;
        }
    }
    if (b == NCHUNK - 1 && t == 255) ctr[0] = exclv + s[255];
}

// duplicate-coordinate losers get appended slots U..N-1
__global__ void k_losers(const int4* __restrict__ coors, const int* __restrict__ grid,
                         int* __restrict__ perm, int* __restrict__ ctr, int n) {
    int j = blockIdx.x * blockDim.x + threadIdx.x;
    if (j >= n) return;
    int4 c = coors[j];
    int flat = ((c.x * SD + c.y) * SH + c.z) * SW + c.w;
    int si = grid[flat];
    if (perm[si] != j) {
        int s = atomicAdd(ctr, 1);
        perm[s] = j;
    }
}

// fs[i] = bf16(features[perm[i]]); fb[i] = flat coord of perm[i]
__global__ void k_permfeat(const float4* __restrict__ feats4, const int4* __restrict__ coors,
                           const int* __restrict__ perm, s16x8* __restrict__ fs,
                           int* __restrict__ fb, int n) {
    int tid = blockIdx.x * blockDim.x + threadIdx.x;
    int i = tid >> 3, j = tid & 7;
    if (i >= n) return;
    int src = perm[i];
    float4 p0 = feats4[(size_t)src * 16 + j * 2];
    float4 p1 = feats4[(size_t)src * 16 + j * 2 + 1];
    fs[(size_t)i * 8 + j] = pack_bf8(p0, p1);
    if (j == 0) {
        int4 c = coors[src];
        fb[i] = ((c.x * SD + c.y) * SH + c.z) * SW + c.w;
    }
}

// ---------- sorted conv v3: LDS weights + software-pipelined gathers ----------
// Per iter k: hoisted bf ds_reads(k) | weight glb loads(k+1) | lookup(k+2) |
// shfl+A-gather issue(k+1) | MFMA(k) | ds_write(k+1) | barrier.
// A-frag (16x16x32): lane holds row lane&15, k-elems (lane>>4)*8+j -> one 16B load.
// C/D: col=lane&15, row=(lane>>4)*4+reg (m89-verified, r4/r5/r9-validated).
template <int OUT_PERM>
__global__ __launch_bounds__(256) void k_conv_s(const s16x8* __restrict__ fin,
                                                const s16x8* __restrict__ wt,
                                                const int* __restrict__ fb,
                                                const int* __restrict__ grid,
                                                const int* __restrict__ perm,
                                                void* __restrict__ outp, int n) {
    __shared__ s16x8 wbuf[2][512];  // 2 x 8 KB double-buffered weight slice

    // bijective XCD-chunked swizzle (m204)
    int nwg = gridDim.x, orig = blockIdx.x;
    int q = nwg >> 3, rr = nwg & 7;
    int xcd = orig & 7, bidx = orig >> 3;
    int blk = (xcd < rr ? xcd * (q + 1) : rr * (q + 1) + (xcd - rr) * q) + bidx;

    int tid = threadIdx.x;
    int w = tid >> 6, lane = tid & 63;
    int wid = blk * 4 + w;
    int base = wid * 32;                 // may be >= n for tail waves: no early return (barriers)
    int r = lane & 15;
    int g = lane >> 4;
    int li = lane & 31;
    int myrow = base + li;
    int rowok = (myrow < n) ? 1 : 0;
    int fbv = fb[rowok ? myrow : 0];
    int pl = 0;
    if (OUT_PERM) pl = rowok ? perm[myrow] : 0;
    int z = (fbv >> 14) & 127, y = (fbv >> 7) & 127, x = fbv & 127;

    f32x4 acc[2][4] = {};

    auto lookup = [&](int k) -> int {
        int dz = k / 9 - 1, dy = (k / 3) % 3 - 1, dx = k % 3 - 1;
        int zz = z + dz, yy = y + dy, xx = x + dx;
        int v = -1;
        if (rowok && (unsigned)zz < SD && (unsigned)yy < SH && (unsigned)xx < SW)
            v = grid[fbv + dz * (SH * SW) + dy * SW + dx];
        return v;
    };

    // prologue: stage weight slice 0; prefetch lookups(0,1) and A-rows(0)
    wbuf[0][tid] = wt[tid];
    wbuf[0][256 + tid] = wt[256 + tid];

    int nbrB;                                  // holds lookup(k+1)
    unsigned long long m0c, m1c;
    s16x8 ca00 = {}, ca01 = {}, ca10 = {}, ca11 = {};
    {
        int nbrA = lookup(0);
        nbrB = lookup(1);
        int nb0 = __shfl(nbrA, r), nb1 = __shfl(nbrA, 16 + r);
        m0c = __ballot(nb0 >= 0);
        m1c = __ballot(nb1 >= 0);
        if (nb0 >= 0) { ca00 = fin[(size_t)nb0 * 8 + g]; ca01 = fin[(size_t)nb0 * 8 + 4 + g]; }
        if (nb1 >= 0) { ca10 = fin[(size_t)nb1 * 8 + g]; ca11 = fin[(size_t)nb1 * 8 + 4 + g]; }
    }
    __syncthreads();

    for (int k = 0; k < KV; ++k) {
        // 1. weight frags for k from LDS (hoisted; latency hides under issue work)
        s16x8 bf[2][4];
        const s16x8* wb = &wbuf[k & 1][0];
#pragma unroll
        for (int s = 0; s < 2; ++s)
#pragma unroll
            for (int t = 0; t < 4; ++t)
                bf[s][t] = wb[(s * 4 + g) * 64 + t * 16 + r];

        // 2. global weight loads for k+1
        int kn = (k + 1 < KV) ? k + 1 : KV - 1;
        s16x8 st0 = wt[(size_t)kn * 512 + tid];
        s16x8 st1 = wt[(size_t)kn * 512 + 256 + tid];

        // 3. grid lookup for k+2
        int nbrC = (k + 2 < KV) ? lookup(k + 2) : -1;

        // 4. distribute nb(k+1), issue A-row gathers for k+1
        int nb0n = __shfl(nbrB, r), nb1n = __shfl(nbrB, 16 + r);
        unsigned long long m0n = __ballot(nb0n >= 0);
        unsigned long long m1n = __ballot(nb1n >= 0);
        s16x8 na00 = {}, na01 = {}, na10 = {}, na11 = {};
        if (nb0n >= 0) { na00 = fin[(size_t)nb0n * 8 + g]; na01 = fin[(size_t)nb0n * 8 + 4 + g]; }
        if (nb1n >= 0) { na10 = fin[(size_t)nb1n * 8 + g]; na11 = fin[(size_t)nb1n * 8 + 4 + g]; }

        // 5. MFMA(k) on prefetched rows
        if (m0c) {
#pragma unroll
            for (int t = 0; t < 4; ++t) {
                acc[0][t] = __builtin_amdgcn_mfma_f32_16x16x32_bf16(ca00, bf[0][t], acc[0][t], 0, 0, 0);
                acc[0][t] = __builtin_amdgcn_mfma_f32_16x16x32_bf16(ca01, bf[1][t], acc[0][t], 0, 0, 0);
            }
        }
        if (m1c) {
#pragma unroll
            for (int t = 0; t < 4; ++t) {
                acc[1][t] = __builtin_amdgcn_mfma_f32_16x16x32_bf16(ca10, bf[0][t], acc[1][t], 0, 0, 0);
                acc[1][t] = __builtin_amdgcn_mfma_f32_16x16x32_bf16(ca11, bf[1][t], acc[1][t], 0, 0, 0);
            }
        }

        // 6. stage next weight slice, barrier
        wbuf[(k + 1) & 1][tid] = st0;
        wbuf[(k + 1) & 1][256 + tid] = st1;
        __syncthreads();

        // 7. rotate pipeline
        nbrB = nbrC;
        ca00 = na00; ca01 = na01; ca10 = na10; ca11 = na11;
        m0c = m0n; m1c = m1n;
    }

    if (OUT_PERM) {
        float* __restrict__ o = (float*)outp;  // scatter back to original row order
#pragma unroll
        for (int h = 0; h < 2; ++h)
#pragma unroll
            for (int t = 0; t < 4; ++t)
#pragma unroll
                for (int j = 0; j < 4; ++j) {
                    int ww = h * 16 + g * 4 + j;
                    if (base + ww < n) {
                        int orow = __shfl(pl, ww);
                        o[(size_t)orow * 64 + t * 16 + r] = acc[h][t][j];
                    }
                }
    } else {
        unsigned short* __restrict__ o = (unsigned short*)outp;  // sorted bf16 intermediate
#pragma unroll
        for (int h = 0; h < 2; ++h)
#pragma unroll
            for (int t = 0; t < 4; ++t)
#pragma unroll
                for (int j = 0; j < 4; ++j) {
                    int row = base + h * 16 + g * 4 + j;
                    if (row < n) o[(size_t)row * 64 + t * 16 + r] = f2bf_rne(acc[h][t][j]);
                }
    }
}

extern "C" void kernel_launch(void* const* d_in, const int* in_sizes, int n_in,
                              void* d_out, int out_size, void* d_ws, size_t ws_size,
                              hipStream_t stream) {
    const float* feats = (const float*)d_in[0];
    const int4* coors = (const int4*)d_in[1];
    const float* W0 = (const float*)d_in[2];
    const float* W1 = (const float*)d_in[3];
    int N = in_sizes[0] / CCH;

    char* p = (char*)d_ws;
    auto carve = [&](size_t bytes) -> char* {
        char* q = p;
        p += (bytes + 255) & ~(size_t)255;
        return q;
    };

    size_t grid_bytes = (size_t)NCELL * 4;
    int* grid = (int*)carve(grid_bytes);                                 // 16.78 MB
    unsigned short* wt0 = (unsigned short*)carve((size_t)NWELEM * 2);
    unsigned short* wt1 = (unsigned short*)carve((size_t)NWELEM * 2);
    int* counts = (int*)carve(NCHUNK * 4);
    int* ctr = (int*)carve(256);
    int* perm = (int*)carve((size_t)N * 4);
    int* fb = (int*)carve((size_t)N * 4);
    s16x8* fs = (s16x8*)carve((size_t)N * CCH * 2);                      // 25.6 MB
    s16x8* ibf_s = (s16x8*)carve((size_t)N * CCH * 2);                   // 25.6 MB (~70.3 MB total, fits: r5/r9)

    int tiles = (N + 31) / 32;
    int blocks = (tiles + 3) / 4;

    hipMemsetAsync(grid, 0xFF, grid_bytes, stream);
    k_wprep2<<<(2 * NWELEM + 255) / 256, 256, 0, stream>>>(W0, W1, wt0, wt1);
    k_scatter<<<(N + 255) / 256, 256, 0, stream>>>(coors, grid, N);
    k_count<<<NCHUNK, 256, 0, stream>>>((const int4*)grid, counts);
    k_compact<<<NCHUNK, 256, 0, stream>>>(grid, counts, perm, ctr);
    k_losers<<<(N + 255) / 256, 256, 0, stream>>>(coors, grid, perm, ctr, N);
    k_permfeat<<<((N * 8) + 255) / 256, 256, 0, stream>>>((const float4*)feats, coors, perm, fs, fb, N);
    k_conv_s<0><<<blocks, 256, 0, stream>>>(fs, (const s16x8*)wt0, fb, grid, perm, ibf_s, N);
    k_conv_s<1><<<blocks, 256, 0, stream>>>(ibf_s, (const s16x8*)wt1, fb, grid, perm, d_out, N);
}